// Round 9
// baseline (65.633 us; speedup 1.0000x reference)
//
#include <hip/hip_runtime.h>
#include <hip/hip_bf16.h>
#include <stdint.h>

typedef __bf16 bf16_t;
typedef __bf16 bf16x8 __attribute__((ext_vector_type(8)));
typedef float f32x4 __attribute__((ext_vector_type(4)));

#define L2E 1.44269504088896340736f

static __device__ __forceinline__ f32x4 mfma16(bf16x8 a, bf16x8 b, f32x4 c) {
  return __builtin_amdgcn_mfma_f32_16x16x32_bf16(a, b, c, 0, 0, 0);
}

// ---------------- kernel 0: weights -> bf16, transposed to [proj][n=64][k=1024] ----
// proj 0 (Q) folds the 1/sqrt(64) scale.
__global__ __launch_bounds__(256) void wt_kernel(const float* __restrict__ Wq,
                                                 const float* __restrict__ Wk,
                                                 const float* __restrict__ Wv,
                                                 bf16_t* __restrict__ Wt) {
  int gid = blockIdx.x * 256 + threadIdx.x;  // 0 .. 196607
  int proj = gid >> 16;
  int rem = gid & 65535;          // = k*64 + n (row-major read, coalesced)
  int k = rem >> 6, n = rem & 63;
  const float* W = (proj == 0) ? Wq : (proj == 1) ? Wk : Wv;
  float v = W[rem];
  if (proj == 0) v *= 0.125f;
  Wt[proj * 65536 + n * 1024 + k] = (bf16_t)v;
}

// ---------------- kernel 1: QKV projection — many small independent blocks ---------
// grid 1536 (6/CU), block 256 (4 waves) = 24 waves/CU. Block owns ONE 16-row tile;
// wave w computes k-quarter [256w,256w+256). A-frags and W-frags loaded DIRECTLY
// from global (full-64B-line scattered requests), depth-2 software pipeline, W is
// L2-resident. Single k-merge barrier per block; LDS only for the merge (padded).
__global__ __launch_bounds__(256, 4) void proj_kernel(
    const float* __restrict__ Xq, const float* __restrict__ Xk, const float* __restrict__ Xv,
    const bf16_t* __restrict__ Wt,
    bf16_t* __restrict__ Qb, bf16_t* __restrict__ Kb, bf16_t* __restrict__ Vt) {
  __shared__ float Msm[4][16][68];   // k-merge partials, pad->conflict-light
  __shared__ bf16_t Vsm[16][68];     // V transpose staging

  int tid = threadIdx.x;
  int w = tid >> 6, lane = tid & 63;
  int l15 = lane & 15, g = lane >> 4;
  int bid = blockIdx.x;
  int p = bid >> 9, t = bid & 511;
  int m0 = t * 16;
  const float* X = (p == 0) ? Xq : (p == 1) ? Xk : Xv;

  const float* xk = X + (size_t)(m0 + l15) * 1024 + w * 256 + g * 8;
  const bf16_t* wrow = Wt + p * 65536 + l15 * 1024 + w * 256 + g * 8;

  f32x4 acc[4] = {};

  float4 a0x = *(const float4*)xk;
  float4 a0y = *(const float4*)(xk + 4);
  bf16x8 w0[4], w1[4];
#pragma unroll
  for (int ct = 0; ct < 4; ++ct) w0[ct] = *(const bf16x8*)(wrow + ct * 16384);

  float4 a1x, a1y;
#pragma unroll
  for (int ks = 0; ks < 8; ++ks) {
    if (ks < 7) {
      const float* xn = xk + (ks + 1) * 32;
      a1x = *(const float4*)xn;
      a1y = *(const float4*)(xn + 4);
#pragma unroll
      for (int ct = 0; ct < 4; ++ct)
        w1[ct] = *(const bf16x8*)(wrow + ct * 16384 + (ks + 1) * 32);
    }
    bf16x8 af;
    af[0] = (bf16_t)a0x.x; af[1] = (bf16_t)a0x.y; af[2] = (bf16_t)a0x.z; af[3] = (bf16_t)a0x.w;
    af[4] = (bf16_t)a0y.x; af[5] = (bf16_t)a0y.y; af[6] = (bf16_t)a0y.z; af[7] = (bf16_t)a0y.w;
#pragma unroll
    for (int ct = 0; ct < 4; ++ct) acc[ct] = mfma16(af, w0[ct], acc[ct]);
    a0x = a1x; a0y = a1y;
#pragma unroll
    for (int ct = 0; ct < 4; ++ct) w0[ct] = w1[ct];
  }

  // ---- 4-way k-merge (one barrier) ----
#pragma unroll
  for (int ct = 0; ct < 4; ++ct)
#pragma unroll
    for (int r = 0; r < 4; ++r)
      Msm[w][g * 4 + r][ct * 16 + l15] = acc[ct][r];
  __syncthreads();

  int row = tid >> 4, c0 = (tid & 15) * 4;
  f32x4 s = *(const f32x4*)&Msm[0][row][c0];
#pragma unroll
  for (int w2 = 1; w2 < 4; ++w2) {
    f32x4 q = *(const f32x4*)&Msm[w2][row][c0];
    s[0] += q[0]; s[1] += q[1]; s[2] += q[2]; s[3] += q[3];
  }

  if (p < 2) {
    bf16_t* Ob = (p == 0) ? Qb : Kb;
    bf16_t o4[4] = {(bf16_t)s[0], (bf16_t)s[1], (bf16_t)s[2], (bf16_t)s[3]};
    *(uint2*)&Ob[(size_t)(m0 + row) * 64 + c0] = *(const uint2*)o4;
  } else {
#pragma unroll
    for (int i = 0; i < 4; ++i) Vsm[row][c0 + i] = (bf16_t)s[i];
    __syncthreads();
    if (tid < 128) {
      int d = tid >> 1, h = tid & 1;
      int b = t >> 7;
      int s_ = (t & 127) * 16 + h * 8;
      bf16_t tmp[8];
#pragma unroll
      for (int i = 0; i < 8; ++i) tmp[i] = Vsm[h * 8 + i][d];
      *(uint4*)(Vt + ((size_t)(b * 64 + d)) * 2048 + s_) = *(const uint4*)tmp;
    }
  }
}

// ---------------- kernel 2: causal flash attention, QBLK=32, KV-split 8 waves ------
// grid (64, 4), block 512 (8 waves), ~1 block/CU. Block owns 32 q-rows (2 row-groups
// per wave); wave w handles KV tiles w, w+8, ... with private flash state; merged at
// the end via LDS. K/V frags straight from L2/L3; no barriers in the main loop.
#define NW 8
__global__ __launch_bounds__(512) void attn_kernel(
    const bf16_t* __restrict__ Qb, const bf16_t* __restrict__ Kb,
    const bf16_t* __restrict__ Vt, float* __restrict__ Out) {
  __shared__ alignas(16) char Psm[NW * 4096];   // per-wave 32x64 P tiles (swizzled)
  __shared__ float accL[NW][32][64];            // 64 KB
  __shared__ float mL[NW][32];
  __shared__ float lL[NW][32];

  int b = blockIdx.y;
  int x = blockIdx.x;
  int qt = (b >= 2) ? (63 - x) : x;    // pair heavy+light across CUs
  int q0 = qt * 32;
  int tid = threadIdx.x;
  int w = tid >> 6, lane = tid & 63;
  int l15 = lane & 15, g = lane >> 4;
  char* Pw = Psm + w * 4096;

  bf16x8 qf[2][2];
#pragma unroll
  for (int h = 0; h < 2; ++h) {
    size_t qrow = (size_t)(b * 2048 + q0 + h * 16 + l15) * 64;
    qf[h][0] = *(const bf16x8*)(Qb + qrow + g * 8);
    qf[h][1] = *(const bf16x8*)(Qb + qrow + 32 + g * 8);
  }

  float m_run[2][4], l_run[2][4];
  f32x4 acc_o[2][4] = {};
#pragma unroll
  for (int h = 0; h < 2; ++h)
#pragma unroll
    for (int r = 0; r < 4; ++r) { m_run[h][r] = -1e30f; l_run[h][r] = 0.f; }

  int ntiles = (q0 + 95) >> 6;         // ceil((q0+32)/64)
  const bf16_t* kbase = Kb + (size_t)b * 2048 * 64;
  const bf16_t* vbase = Vt + (size_t)b * 64 * 2048;

  for (int t = w; t < ntiles; t += NW) {
    int kv0 = t * 64;
    // S = Q K^T  (K frags shared across the two row-groups)
    f32x4 s[2][4] = {};
#pragma unroll
    for (int ct = 0; ct < 4; ++ct) {
      const bf16_t* kr = kbase + (size_t)(kv0 + ct * 16 + l15) * 64 + g * 8;
      bf16x8 kf0 = *(const bf16x8*)kr;
      bf16x8 kf1 = *(const bf16x8*)(kr + 32);
#pragma unroll
      for (int h = 0; h < 2; ++h) {
        s[h][ct] = mfma16(qf[h][0], kf0, s[h][ct]);
        s[h][ct] = mfma16(qf[h][1], kf1, s[h][ct]);
      }
    }
    if (t == ntiles - 1) {  // diagonal tile: causal mask
#pragma unroll
      for (int h = 0; h < 2; ++h)
#pragma unroll
        for (int ct = 0; ct < 4; ++ct)
#pragma unroll
          for (int r = 0; r < 4; ++r) {
            int kg_ = kv0 + ct * 16 + l15;
            int qg_ = q0 + h * 16 + g * 4 + r;
            if (kg_ > qg_) s[h][ct][r] = -1e30f;
          }
    }

    // online softmax (row = h*16 + g*4 + r)
#pragma unroll
    for (int h = 0; h < 2; ++h)
#pragma unroll
      for (int r = 0; r < 4; ++r) {
        float mx = fmaxf(fmaxf(s[h][0][r], s[h][1][r]), fmaxf(s[h][2][r], s[h][3][r]));
        mx = fmaxf(mx, __shfl_xor(mx, 1, 64));
        mx = fmaxf(mx, __shfl_xor(mx, 2, 64));
        mx = fmaxf(mx, __shfl_xor(mx, 4, 64));
        mx = fmaxf(mx, __shfl_xor(mx, 8, 64));
        float mnew = fmaxf(m_run[h][r], mx);
        float scale = exp2f((m_run[h][r] - mnew) * L2E);
        m_run[h][r] = mnew;
        float ps = 0.f;
        int qrl = h * 16 + g * 4 + r;
        char* pb = Pw + qrl * 128;
        int swp = (qrl & 7) << 4;
#pragma unroll
        for (int ct = 0; ct < 4; ++ct) {
          float p = exp2f((s[h][ct][r] - mnew) * L2E);
          ps += p;
          *(bf16_t*)(pb + ((ct * 32 + l15 * 2) ^ swp)) = (bf16_t)p;
        }
        ps += __shfl_xor(ps, 1, 64);
        ps += __shfl_xor(ps, 2, 64);
        ps += __shfl_xor(ps, 4, 64);
        ps += __shfl_xor(ps, 8, 64);
        l_run[h][r] = l_run[h][r] * scale + ps;
#pragma unroll
        for (int dt = 0; dt < 4; ++dt) acc_o[h][dt][r] *= scale;
      }

    // O += P V   (V frags shared across the two row-groups)
    int swpr = (l15 & 7) << 4;
#pragma unroll
    for (int ks = 0; ks < 2; ++ks) {
      bf16x8 pf0 = *(const bf16x8*)(Pw + l15 * 128 + ((ks * 64 + g * 16) ^ swpr));
      bf16x8 pf1 = *(const bf16x8*)(Pw + (16 + l15) * 128 + ((ks * 64 + g * 16) ^ swpr));
#pragma unroll
      for (int dt = 0; dt < 4; ++dt) {
        const bf16_t* vr = vbase + (size_t)(dt * 16 + l15) * 2048 + kv0 + ks * 32 + g * 8;
        bf16x8 vf = *(const bf16x8*)vr;
        acc_o[0][dt] = mfma16(pf0, vf, acc_o[0][dt]);
        acc_o[1][dt] = mfma16(pf1, vf, acc_o[1][dt]);
      }
    }
  }

  // publish per-wave partial state
  if (l15 == 0) {
#pragma unroll
    for (int h = 0; h < 2; ++h)
#pragma unroll
      for (int r = 0; r < 4; ++r) {
        mL[w][h * 16 + g * 4 + r] = m_run[h][r];
        lL[w][h * 16 + g * 4 + r] = l_run[h][r];
      }
  }
#pragma unroll
  for (int h = 0; h < 2; ++h)
#pragma unroll
    for (int dt = 0; dt < 4; ++dt)
#pragma unroll
      for (int r = 0; r < 4; ++r)
        accL[w][h * 16 + g * 4 + r][dt * 16 + l15] = acc_o[h][dt][r];
  __syncthreads();

  // merge 8 partials: thread -> (row = tid>>4, 4 d's = (tid&15)*4)
  int row = tid >> 4, c0 = (tid & 15) * 4;
  float M = -1e30f;
#pragma unroll
  for (int w2 = 0; w2 < NW; ++w2) M = fmaxf(M, mL[w2][row]);
  float L = 0.f;
  f32x4 o = {0.f, 0.f, 0.f, 0.f};
#pragma unroll
  for (int w2 = 0; w2 < NW; ++w2) {
    float sc = exp2f((mL[w2][row] - M) * L2E);
    L += lL[w2][row] * sc;
    f32x4 a = *(const f32x4*)&accL[w2][row][c0];
    o[0] += sc * a[0]; o[1] += sc * a[1]; o[2] += sc * a[2]; o[3] += sc * a[3];
  }
  float inv = 1.0f / L;
  float4 o4 = {o[0] * inv, o[1] * inv, o[2] * inv, o[3] * inv};
  *(float4*)&Out[(size_t)(b * 2048 + q0 + row) * 64 + c0] = o4;
}

extern "C" void kernel_launch(void* const* d_in, const int* in_sizes, int n_in,
                              void* d_out, int out_size, void* d_ws, size_t ws_size,
                              hipStream_t stream) {
  const float* Xk = (const float*)d_in[0];
  const float* Xv = (const float*)d_in[1];
  const float* Xq = (const float*)d_in[2];
  const float* Wq = (const float*)d_in[3];
  const float* Wk = (const float*)d_in[4];
  const float* Wv = (const float*)d_in[5];
  float* Out = (float*)d_out;

  bf16_t* ws = (bf16_t*)d_ws;
  bf16_t* Qb = ws;                 // [8192][64]   bf16, pre-scaled by 0.125
  bf16_t* Kb = ws + 524288;        // [8192][64]   bf16
  bf16_t* Vt = ws + 1048576;       // [4][64][2048] bf16 (V transposed)
  bf16_t* Wt = ws + 1572864;       // [3][64][1024] bf16 (weights transposed)

  wt_kernel<<<dim3(768), dim3(256), 0, stream>>>(Wq, Wk, Wv, Wt);
  proj_kernel<<<dim3(1536), dim3(256), 0, stream>>>(Xq, Xk, Xv, Wt, Qb, Kb, Vt);
  attn_kernel<<<dim3(64, 4), dim3(512), 0, stream>>>(Qb, Kb, Vt, Out);
}

// Round 10
// 65.000 us; speedup vs baseline: 1.0097x; 1.0097x over previous
//
#include <hip/hip_runtime.h>
#include <hip/hip_bf16.h>
#include <stdint.h>

typedef __bf16 bf16_t;
typedef __bf16 bf16x8 __attribute__((ext_vector_type(8)));
typedef float f32x4 __attribute__((ext_vector_type(4)));

#define L2E 1.44269504088896340736f

static __device__ __forceinline__ f32x4 mfma16(bf16x8 a, bf16x8 b, f32x4 c) {
  return __builtin_amdgcn_mfma_f32_16x16x32_bf16(a, b, c, 0, 0, 0);
}

static __device__ __forceinline__ void gload_lds16(const void* g, void* l) {
  __builtin_amdgcn_global_load_lds(
      (const __attribute__((address_space(1))) uint32_t*)g,
      (__attribute__((address_space(3))) uint32_t*)l, 16, 0, 0);
}

// ---------------- kernel 0: weights -> bf16, transposed to [proj][n=64][k=1024] ----
// proj 0 (Q) folds the 1/sqrt(64) scale.
__global__ __launch_bounds__(256) void wt_kernel(const float* __restrict__ Wq,
                                                 const float* __restrict__ Wk,
                                                 const float* __restrict__ Wv,
                                                 bf16_t* __restrict__ Wt) {
  int gid = blockIdx.x * 256 + threadIdx.x;  // 0 .. 196607
  int proj = gid >> 16;
  int rem = gid & 65535;          // = k*64 + n (row-major read, coalesced)
  int k = rem >> 6, n = rem & 63;
  const float* W = (proj == 0) ? Wq : (proj == 1) ? Wk : Wv;
  float v = W[rem];
  if (proj == 0) v *= 0.125f;
  Wt[proj * 65536 + n * 1024 + k] = (bf16_t)v;
}

// ---------------- kernel 1: QKV projection — decoupled waves, contiguous staging ---
// grid 1536, block 256 (4 waves), 2 blocks/CU (64KB LDS). Block owns ONE 16-row
// tile; wave w owns k-quarter [256w,256w+256). Wave w issues its OWN 16 x 1KB-
// contiguous gload_lds (src XOR r<<4, rule #21) + 32 W-frag loads (L2-resident,
// held in 128 VGPR), waits its own vmcnt(0) — no barrier gates any load. Block
// syncs only at the 4-way k-merge (LDS overlay). Read swizzle l15<<4 -> 4-way.
__global__ __launch_bounds__(256, 2) void proj_kernel(
    const float* __restrict__ Xq, const float* __restrict__ Xk, const float* __restrict__ Xv,
    const bf16_t* __restrict__ Wt,
    bf16_t* __restrict__ Qb, bf16_t* __restrict__ Kb, bf16_t* __restrict__ Vt) {
  __shared__ alignas(16) char Xs[65536];   // 4 waves x [16 rows][1KB] f32, swizzled
  float (*Msm)[16][68] = (float(*)[16][68])Xs;            // merge overlay, 17.4 KB
  bf16_t (*Vsm)[68] = (bf16_t(*)[68])(Xs + 18432);        // V transpose overlay

  int tid = threadIdx.x;
  int w = tid >> 6, lane = tid & 63;
  int l15 = lane & 15, g = lane >> 4;
  int bid = blockIdx.x;
  int p = bid >> 9, t = bid & 511;
  int m0 = t * 16;
  const float* X = (p == 0) ? Xq : (p == 1) ? Xk : Xv;
  const char* xb = (const char*)X + (size_t)m0 * 4096;
  char* Xw = Xs + w * 16384;

  // ---- W fragments: full k-slice in registers (32 scattered L2-resident loads) ----
  bf16x8 Wf[4][8];
  const bf16_t* wrow = Wt + p * 65536 + l15 * 1024 + w * 256 + g * 8;
#pragma unroll
  for (int ct = 0; ct < 4; ++ct)
#pragma unroll
    for (int j = 0; j < 8; ++j)
      Wf[ct][j] = *(const bf16x8*)(wrow + ct * 16384 + j * 32);

  // ---- X staging: 16 x 1KB-contiguous instrs, wave-private ----
#pragma unroll
  for (int r = 0; r < 16; ++r) {
    const char* src = xb + (size_t)r * 4096 + w * 1024 + ((lane * 16) ^ (r << 4));
    gload_lds16(src, Xw + r * 1024);
  }
  asm volatile("s_waitcnt vmcnt(0)" ::: "memory");
  __builtin_amdgcn_sched_barrier(0);

  // ---- compute: 8 k-steps from swizzled LDS + W regs ----
  f32x4 acc[4] = {};
  const char* bp = Xw + l15 * 1024;
  int swz = l15 << 4;
#pragma unroll
  for (int j = 0; j < 8; ++j) {
    int b0 = j * 128 + g * 32;
    float4 u0 = *(const float4*)(bp + (b0 ^ swz));
    float4 u1 = *(const float4*)(bp + ((b0 + 16) ^ swz));
    bf16x8 af;
    af[0] = (bf16_t)u0.x; af[1] = (bf16_t)u0.y; af[2] = (bf16_t)u0.z; af[3] = (bf16_t)u0.w;
    af[4] = (bf16_t)u1.x; af[5] = (bf16_t)u1.y; af[6] = (bf16_t)u1.z; af[7] = (bf16_t)u1.w;
#pragma unroll
    for (int ct = 0; ct < 4; ++ct)
      acc[ct] = mfma16(af, Wf[ct][j], acc[ct]);
  }

  // ---- 4-way k-merge via LDS overlay (only block-wide sync) ----
  __syncthreads();               // all waves done reading Xs
#pragma unroll
  for (int ct = 0; ct < 4; ++ct)
#pragma unroll
    for (int r = 0; r < 4; ++r)
      Msm[w][g * 4 + r][ct * 16 + l15] = acc[ct][r];
  __syncthreads();

  int row = tid >> 4, c0 = (tid & 15) * 4;
  f32x4 s = *(const f32x4*)&Msm[0][row][c0];
#pragma unroll
  for (int w2 = 1; w2 < 4; ++w2) {
    f32x4 q = *(const f32x4*)&Msm[w2][row][c0];
    s[0] += q[0]; s[1] += q[1]; s[2] += q[2]; s[3] += q[3];
  }

  if (p < 2) {
    bf16_t* Ob = (p == 0) ? Qb : Kb;
    bf16_t o4[4] = {(bf16_t)s[0], (bf16_t)s[1], (bf16_t)s[2], (bf16_t)s[3]};
    *(uint2*)&Ob[(size_t)(m0 + row) * 64 + c0] = *(const uint2*)o4;
  } else {
#pragma unroll
    for (int i = 0; i < 4; ++i) Vsm[row][c0 + i] = (bf16_t)s[i];
    __syncthreads();
    if (tid < 128) {
      int d = tid >> 1, h = tid & 1;
      int b = t >> 7;
      int s_ = (t & 127) * 16 + h * 8;
      bf16_t tmp[8];
#pragma unroll
      for (int i = 0; i < 8; ++i) tmp[i] = Vsm[h * 8 + i][d];
      *(uint4*)(Vt + ((size_t)(b * 64 + d)) * 2048 + s_) = *(const uint4*)tmp;
    }
  }
}

// ---------------- kernel 2: causal flash attention, QBLK=32, KV-split 8 waves ------
// grid (64, 4), block 512 (8 waves), ~1 block/CU. Block owns 32 q-rows (2 row-groups
// per wave); wave w handles KV tiles w, w+8, ... with private flash state; merged at
// the end via LDS. K/V frags straight from L2/L3; no barriers in the main loop.
#define NW 8
__global__ __launch_bounds__(512) void attn_kernel(
    const bf16_t* __restrict__ Qb, const bf16_t* __restrict__ Kb,
    const bf16_t* __restrict__ Vt, float* __restrict__ Out) {
  __shared__ alignas(16) char Psm[NW * 4096];   // per-wave 32x64 P tiles (swizzled)
  __shared__ float accL[NW][32][64];            // 64 KB
  __shared__ float mL[NW][32];
  __shared__ float lL[NW][32];

  int b = blockIdx.y;
  int x = blockIdx.x;
  int qt = (b >= 2) ? (63 - x) : x;    // pair heavy+light across CUs
  int q0 = qt * 32;
  int tid = threadIdx.x;
  int w = tid >> 6, lane = tid & 63;
  int l15 = lane & 15, g = lane >> 4;
  char* Pw = Psm + w * 4096;

  bf16x8 qf[2][2];
#pragma unroll
  for (int h = 0; h < 2; ++h) {
    size_t qrow = (size_t)(b * 2048 + q0 + h * 16 + l15) * 64;
    qf[h][0] = *(const bf16x8*)(Qb + qrow + g * 8);
    qf[h][1] = *(const bf16x8*)(Qb + qrow + 32 + g * 8);
  }

  float m_run[2][4], l_run[2][4];
  f32x4 acc_o[2][4] = {};
#pragma unroll
  for (int h = 0; h < 2; ++h)
#pragma unroll
    for (int r = 0; r < 4; ++r) { m_run[h][r] = -1e30f; l_run[h][r] = 0.f; }

  int ntiles = (q0 + 95) >> 6;         // ceil((q0+32)/64)
  const bf16_t* kbase = Kb + (size_t)b * 2048 * 64;
  const bf16_t* vbase = Vt + (size_t)b * 64 * 2048;

  for (int t = w; t < ntiles; t += NW) {
    int kv0 = t * 64;
    // S = Q K^T  (K frags shared across the two row-groups)
    f32x4 s[2][4] = {};
#pragma unroll
    for (int ct = 0; ct < 4; ++ct) {
      const bf16_t* kr = kbase + (size_t)(kv0 + ct * 16 + l15) * 64 + g * 8;
      bf16x8 kf0 = *(const bf16x8*)kr;
      bf16x8 kf1 = *(const bf16x8*)(kr + 32);
#pragma unroll
      for (int h = 0; h < 2; ++h) {
        s[h][ct] = mfma16(qf[h][0], kf0, s[h][ct]);
        s[h][ct] = mfma16(qf[h][1], kf1, s[h][ct]);
      }
    }
    if (t == ntiles - 1) {  // diagonal tile: causal mask
#pragma unroll
      for (int h = 0; h < 2; ++h)
#pragma unroll
        for (int ct = 0; ct < 4; ++ct)
#pragma unroll
          for (int r = 0; r < 4; ++r) {
            int kg_ = kv0 + ct * 16 + l15;
            int qg_ = q0 + h * 16 + g * 4 + r;
            if (kg_ > qg_) s[h][ct][r] = -1e30f;
          }
    }

    // online softmax (row = h*16 + g*4 + r)
#pragma unroll
    for (int h = 0; h < 2; ++h)
#pragma unroll
      for (int r = 0; r < 4; ++r) {
        float mx = fmaxf(fmaxf(s[h][0][r], s[h][1][r]), fmaxf(s[h][2][r], s[h][3][r]));
        mx = fmaxf(mx, __shfl_xor(mx, 1, 64));
        mx = fmaxf(mx, __shfl_xor(mx, 2, 64));
        mx = fmaxf(mx, __shfl_xor(mx, 4, 64));
        mx = fmaxf(mx, __shfl_xor(mx, 8, 64));
        float mnew = fmaxf(m_run[h][r], mx);
        float scale = exp2f((m_run[h][r] - mnew) * L2E);
        m_run[h][r] = mnew;
        float ps = 0.f;
        int qrl = h * 16 + g * 4 + r;
        char* pb = Pw + qrl * 128;
        int swp = (qrl & 7) << 4;
#pragma unroll
        for (int ct = 0; ct < 4; ++ct) {
          float p = exp2f((s[h][ct][r] - mnew) * L2E);
          ps += p;
          *(bf16_t*)(pb + ((ct * 32 + l15 * 2) ^ swp)) = (bf16_t)p;
        }
        ps += __shfl_xor(ps, 1, 64);
        ps += __shfl_xor(ps, 2, 64);
        ps += __shfl_xor(ps, 4, 64);
        ps += __shfl_xor(ps, 8, 64);
        l_run[h][r] = l_run[h][r] * scale + ps;
#pragma unroll
        for (int dt = 0; dt < 4; ++dt) acc_o[h][dt][r] *= scale;
      }

    // O += P V   (V frags shared across the two row-groups)
    int swpr = (l15 & 7) << 4;
#pragma unroll
    for (int ks = 0; ks < 2; ++ks) {
      bf16x8 pf0 = *(const bf16x8*)(Pw + l15 * 128 + ((ks * 64 + g * 16) ^ swpr));
      bf16x8 pf1 = *(const bf16x8*)(Pw + (16 + l15) * 128 + ((ks * 64 + g * 16) ^ swpr));
#pragma unroll
      for (int dt = 0; dt < 4; ++dt) {
        const bf16_t* vr = vbase + (size_t)(dt * 16 + l15) * 2048 + kv0 + ks * 32 + g * 8;
        bf16x8 vf = *(const bf16x8*)vr;
        acc_o[0][dt] = mfma16(pf0, vf, acc_o[0][dt]);
        acc_o[1][dt] = mfma16(pf1, vf, acc_o[1][dt]);
      }
    }
  }

  // publish per-wave partial state
  if (l15 == 0) {
#pragma unroll
    for (int h = 0; h < 2; ++h)
#pragma unroll
      for (int r = 0; r < 4; ++r) {
        mL[w][h * 16 + g * 4 + r] = m_run[h][r];
        lL[w][h * 16 + g * 4 + r] = l_run[h][r];
      }
  }
#pragma unroll
  for (int h = 0; h < 2; ++h)
#pragma unroll
    for (int dt = 0; dt < 4; ++dt)
#pragma unroll
      for (int r = 0; r < 4; ++r)
        accL[w][h * 16 + g * 4 + r][dt * 16 + l15] = acc_o[h][dt][r];
  __syncthreads();

  // merge 8 partials: thread -> (row = tid>>4, 4 d's = (tid&15)*4)
  int row = tid >> 4, c0 = (tid & 15) * 4;
  float M = -1e30f;
#pragma unroll
  for (int w2 = 0; w2 < NW; ++w2) M = fmaxf(M, mL[w2][row]);
  float L = 0.f;
  f32x4 o = {0.f, 0.f, 0.f, 0.f};
#pragma unroll
  for (int w2 = 0; w2 < NW; ++w2) {
    float sc = exp2f((mL[w2][row] - M) * L2E);
    L += lL[w2][row] * sc;
    f32x4 a = *(const f32x4*)&accL[w2][row][c0];
    o[0] += sc * a[0]; o[1] += sc * a[1]; o[2] += sc * a[2]; o[3] += sc * a[3];
  }
  float inv = 1.0f / L;
  float4 o4 = {o[0] * inv, o[1] * inv, o[2] * inv, o[3] * inv};
  *(float4*)&Out[(size_t)(b * 2048 + q0 + row) * 64 + c0] = o4;
}

extern "C" void kernel_launch(void* const* d_in, const int* in_sizes, int n_in,
                              void* d_out, int out_size, void* d_ws, size_t ws_size,
                              hipStream_t stream) {
  const float* Xk = (const float*)d_in[0];
  const float* Xv = (const float*)d_in[1];
  const float* Xq = (const float*)d_in[2];
  const float* Wq = (const float*)d_in[3];
  const float* Wk = (const float*)d_in[4];
  const float* Wv = (const float*)d_in[5];
  float* Out = (float*)d_out;

  bf16_t* ws = (bf16_t*)d_ws;
  bf16_t* Qb = ws;                 // [8192][64]   bf16, pre-scaled by 0.125
  bf16_t* Kb = ws + 524288;        // [8192][64]   bf16
  bf16_t* Vt = ws + 1048576;       // [4][64][2048] bf16 (V transposed)
  bf16_t* Wt = ws + 1572864;       // [3][64][1024] bf16 (weights transposed)

  wt_kernel<<<dim3(768), dim3(256), 0, stream>>>(Wq, Wk, Wv, Wt);
  proj_kernel<<<dim3(1536), dim3(256), 0, stream>>>(Xq, Xk, Xv, Wt, Qb, Kb, Vt);
  attn_kernel<<<dim3(64, 4), dim3(512), 0, stream>>>(Qb, Kb, Vt, Out);
}

// Round 11
// 54.053 us; speedup vs baseline: 1.2142x; 1.2025x over previous
//
#include <hip/hip_runtime.h>
#include <hip/hip_bf16.h>
#include <stdint.h>

typedef __bf16 bf16_t;
typedef __bf16 bf16x8 __attribute__((ext_vector_type(8)));
typedef float f32x4 __attribute__((ext_vector_type(4)));

#define L2E 1.44269504088896340736f

static __device__ __forceinline__ f32x4 mfma16(bf16x8 a, bf16x8 b, f32x4 c) {
  return __builtin_amdgcn_mfma_f32_16x16x32_bf16(a, b, c, 0, 0, 0);
}

static __device__ __forceinline__ void gload_lds16(const void* g, void* l) {
  __builtin_amdgcn_global_load_lds(
      (const __attribute__((address_space(1))) uint32_t*)g,
      (__attribute__((address_space(3))) uint32_t*)l, 16, 0, 0);
}

// ---------------- kernel 0: weights -> bf16, transposed to [proj][n=64][k=1024] ----
// proj 0 (Q) folds the 1/sqrt(64) scale.
__global__ __launch_bounds__(256) void wt_kernel(const float* __restrict__ Wq,
                                                 const float* __restrict__ Wk,
                                                 const float* __restrict__ Wv,
                                                 bf16_t* __restrict__ Wt) {
  int gid = blockIdx.x * 256 + threadIdx.x;  // 0 .. 196607
  int proj = gid >> 16;
  int rem = gid & 65535;          // = k*64 + n (row-major read, coalesced)
  int k = rem >> 6, n = rem & 63;
  const float* W = (proj == 0) ? Wq : (proj == 1) ? Wk : Wv;
  float v = W[rem];
  if (proj == 0) v *= 0.125f;
  Wt[proj * 65536 + n * 1024 + k] = (bf16_t)v;
}

// ---------------- kernel 1: QKV projection — W-in-LDS once, fully decoupled waves --
// grid 256 (1 block/CU exactly), block 384 (6 waves), LDS 145KB. Preamble: stage the
// block's W[p] (128KB bf16, XOR-swizzled source) into LDS ONCE -> W traffic 33MB
// chip-wide (was 196MB: 2/3 of all read bytes — the real wall). One barrier total.
// Then wave w independently computes tile bid*6+w (16 rows, full K=1024): A-frags
// direct global (full-line scatter, depth-2 pipeline), W-frags swizzled ds_read_b128.
// Straddle blocks (2 of 256): minority-p waves read W frags from global (L2).
__global__ __launch_bounds__(384, 1) void proj_kernel(
    const float* __restrict__ Xq, const float* __restrict__ Xk, const float* __restrict__ Xv,
    const bf16_t* __restrict__ Wt,
    bf16_t* __restrict__ Qb, bf16_t* __restrict__ Kb, bf16_t* __restrict__ Vt) {
  __shared__ alignas(16) char Wl[131072];        // W[p_lds]: [64 n][1024 k] bf16, swz
  __shared__ alignas(16) bf16_t Osm[6][16][72];  // per-wave output staging (padded)

  int tid = threadIdx.x;
  int w = tid / 64, lane = tid & 63;
  int l15 = lane & 15, g = lane >> 4;
  int bid = blockIdx.x;

  int p_lds = (bid * 6 + 2) >> 9;   // proj whose W goes to LDS (majority of waves)

  // ---- stage W[p_lds] -> LDS, once (inverse-swizzled source, linear dest) ----
  {
    const char* wb = (const char*)(Wt + (size_t)p_lds * 65536);
    for (int n = w; n < 64; n += 6) {
#pragma unroll
      for (int h = 0; h < 2; ++h) {
        const char* src = wb + n * 2048 + h * 1024 + ((lane * 16) ^ ((n & 7) << 4));
        gload_lds16(src, Wl + n * 2048 + h * 1024);
      }
    }
  }
  __syncthreads();   // drains vmcnt; the only block-wide barrier

  int T = bid * 6 + w;              // this wave's global tile, < 1536
  int p = T >> 9;
  int t = T & 511;
  int m0 = t * 16;
  const float* X = (p == 0) ? Xq : (p == 1) ? Xk : Xv;
  const float* xrow = X + (size_t)(m0 + l15) * 1024 + g * 8;

  f32x4 acc[4] = {};

  auto wfrag_lds = [&](int ct, int byteoff) -> bf16x8 {
    int n = ct * 16 + l15;
    return *(const bf16x8*)(Wl + n * 2048 + (byteoff ^ ((n & 7) << 4)));
  };
  auto wfrag_glob = [&](int ct, int byteoff) -> bf16x8 {
    int n = ct * 16 + l15;
    return *(const bf16x8*)((const char*)(Wt + (size_t)p * 65536) + n * 2048 + byteoff);
  };

  auto run = [&](auto wf) {
    float4 pa[2][4];
    auto ld = [&](int j, float4* r) {
      const float* b = xrow + j * 64;
      r[0] = *(const float4*)b;        r[1] = *(const float4*)(b + 4);
      r[2] = *(const float4*)(b + 32); r[3] = *(const float4*)(b + 36);
    };
    ld(0, pa[0]);
#pragma unroll
    for (int j = 0; j < 16; ++j) {    // 16 k-steps of 64
      if (j < 15) ld(j + 1, pa[(j + 1) & 1]);
      float4* r = pa[j & 1];
      bf16x8 a0, a1;
      a0[0] = (bf16_t)r[0].x; a0[1] = (bf16_t)r[0].y; a0[2] = (bf16_t)r[0].z; a0[3] = (bf16_t)r[0].w;
      a0[4] = (bf16_t)r[1].x; a0[5] = (bf16_t)r[1].y; a0[6] = (bf16_t)r[1].z; a0[7] = (bf16_t)r[1].w;
      a1[0] = (bf16_t)r[2].x; a1[1] = (bf16_t)r[2].y; a1[2] = (bf16_t)r[2].z; a1[3] = (bf16_t)r[2].w;
      a1[4] = (bf16_t)r[3].x; a1[5] = (bf16_t)r[3].y; a1[6] = (bf16_t)r[3].z; a1[7] = (bf16_t)r[3].w;
#pragma unroll
      for (int ct = 0; ct < 4; ++ct) {
        acc[ct] = mfma16(a0, wf(ct, j * 128 + g * 16), acc[ct]);
        acc[ct] = mfma16(a1, wf(ct, j * 128 + 64 + g * 16), acc[ct]);
      }
    }
  };
  if (p == p_lds) run(wfrag_lds); else run(wfrag_glob);

  // ---- epilogue: per-wave staging -> coalesced stores ----
#pragma unroll
  for (int ct = 0; ct < 4; ++ct)
#pragma unroll
    for (int r = 0; r < 4; ++r)
      Osm[w][g * 4 + r][ct * 16 + l15] = (bf16_t)acc[ct][r];
  // wave-private buffer: compiler inserts the lgkm wait before the re-reads

  if (p < 2) {
    bf16_t* Ob = (p == 0) ? Qb : Kb;
    int row = lane >> 2, c0 = (lane & 3) * 16;
    uint4 v0 = *(const uint4*)&Osm[w][row][c0];
    uint4 v1 = *(const uint4*)&Osm[w][row][c0 + 8];
    *(uint4*)&Ob[(size_t)(m0 + row) * 64 + c0] = v0;
    *(uint4*)&Ob[(size_t)(m0 + row) * 64 + c0 + 8] = v1;
  } else {
    int d = lane;
    bf16_t tmp[16];
#pragma unroll
    for (int s = 0; s < 16; ++s) tmp[s] = Osm[w][s][d];
    int b = t >> 7, s0 = (t & 127) * 16;
    bf16_t* dst = Vt + ((size_t)(b * 64 + d)) * 2048 + s0;
    *(uint4*)dst = *(const uint4*)&tmp[0];
    *(uint4*)(dst + 8) = *(const uint4*)&tmp[8];
  }
}

// ---------------- kernel 2: causal flash attention, QBLK=32, KV-split 8 waves ------
// grid (64, 4), block 512 (8 waves), ~1 block/CU. Block owns 32 q-rows (2 row-groups
// per wave); wave w handles KV tiles w, w+8, ... with private flash state; merged at
// the end via LDS. K/V frags straight from L2/L3; no barriers in the main loop.
#define NW 8
__global__ __launch_bounds__(512) void attn_kernel(
    const bf16_t* __restrict__ Qb, const bf16_t* __restrict__ Kb,
    const bf16_t* __restrict__ Vt, float* __restrict__ Out) {
  __shared__ alignas(16) char Psm[NW * 4096];   // per-wave 32x64 P tiles (swizzled)
  __shared__ float accL[NW][32][64];            // 64 KB
  __shared__ float mL[NW][32];
  __shared__ float lL[NW][32];

  int b = blockIdx.y;
  int x = blockIdx.x;
  int qt = (b >= 2) ? (63 - x) : x;    // pair heavy+light across CUs
  int q0 = qt * 32;
  int tid = threadIdx.x;
  int w = tid >> 6, lane = tid & 63;
  int l15 = lane & 15, g = lane >> 4;
  char* Pw = Psm + w * 4096;

  bf16x8 qf[2][2];
#pragma unroll
  for (int h = 0; h < 2; ++h) {
    size_t qrow = (size_t)(b * 2048 + q0 + h * 16 + l15) * 64;
    qf[h][0] = *(const bf16x8*)(Qb + qrow + g * 8);
    qf[h][1] = *(const bf16x8*)(Qb + qrow + 32 + g * 8);
  }

  float m_run[2][4], l_run[2][4];
  f32x4 acc_o[2][4] = {};
#pragma unroll
  for (int h = 0; h < 2; ++h)
#pragma unroll
    for (int r = 0; r < 4; ++r) { m_run[h][r] = -1e30f; l_run[h][r] = 0.f; }

  int ntiles = (q0 + 95) >> 6;         // ceil((q0+32)/64)
  const bf16_t* kbase = Kb + (size_t)b * 2048 * 64;
  const bf16_t* vbase = Vt + (size_t)b * 64 * 2048;

  for (int t = w; t < ntiles; t += NW) {
    int kv0 = t * 64;
    // S = Q K^T  (K frags shared across the two row-groups)
    f32x4 s[2][4] = {};
#pragma unroll
    for (int ct = 0; ct < 4; ++ct) {
      const bf16_t* kr = kbase + (size_t)(kv0 + ct * 16 + l15) * 64 + g * 8;
      bf16x8 kf0 = *(const bf16x8*)kr;
      bf16x8 kf1 = *(const bf16x8*)(kr + 32);
#pragma unroll
      for (int h = 0; h < 2; ++h) {
        s[h][ct] = mfma16(qf[h][0], kf0, s[h][ct]);
        s[h][ct] = mfma16(qf[h][1], kf1, s[h][ct]);
      }
    }
    if (t == ntiles - 1) {  // diagonal tile: causal mask
#pragma unroll
      for (int h = 0; h < 2; ++h)
#pragma unroll
        for (int ct = 0; ct < 4; ++ct)
#pragma unroll
          for (int r = 0; r < 4; ++r) {
            int kg_ = kv0 + ct * 16 + l15;
            int qg_ = q0 + h * 16 + g * 4 + r;
            if (kg_ > qg_) s[h][ct][r] = -1e30f;
          }
    }

    // online softmax (row = h*16 + g*4 + r)
#pragma unroll
    for (int h = 0; h < 2; ++h)
#pragma unroll
      for (int r = 0; r < 4; ++r) {
        float mx = fmaxf(fmaxf(s[h][0][r], s[h][1][r]), fmaxf(s[h][2][r], s[h][3][r]));
        mx = fmaxf(mx, __shfl_xor(mx, 1, 64));
        mx = fmaxf(mx, __shfl_xor(mx, 2, 64));
        mx = fmaxf(mx, __shfl_xor(mx, 4, 64));
        mx = fmaxf(mx, __shfl_xor(mx, 8, 64));
        float mnew = fmaxf(m_run[h][r], mx);
        float scale = exp2f((m_run[h][r] - mnew) * L2E);
        m_run[h][r] = mnew;
        float ps = 0.f;
        int qrl = h * 16 + g * 4 + r;
        char* pb = Pw + qrl * 128;
        int swp = (qrl & 7) << 4;
#pragma unroll
        for (int ct = 0; ct < 4; ++ct) {
          float p = exp2f((s[h][ct][r] - mnew) * L2E);
          ps += p;
          *(bf16_t*)(pb + ((ct * 32 + l15 * 2) ^ swp)) = (bf16_t)p;
        }
        ps += __shfl_xor(ps, 1, 64);
        ps += __shfl_xor(ps, 2, 64);
        ps += __shfl_xor(ps, 4, 64);
        ps += __shfl_xor(ps, 8, 64);
        l_run[h][r] = l_run[h][r] * scale + ps;
#pragma unroll
        for (int dt = 0; dt < 4; ++dt) acc_o[h][dt][r] *= scale;
      }

    // O += P V   (V frags shared across the two row-groups)
    int swpr = (l15 & 7) << 4;
#pragma unroll
    for (int ks = 0; ks < 2; ++ks) {
      bf16x8 pf0 = *(const bf16x8*)(Pw + l15 * 128 + ((ks * 64 + g * 16) ^ swpr));
      bf16x8 pf1 = *(const bf16x8*)(Pw + (16 + l15) * 128 + ((ks * 64 + g * 16) ^ swpr));
#pragma unroll
      for (int dt = 0; dt < 4; ++dt) {
        const bf16_t* vr = vbase + (size_t)(dt * 16 + l15) * 2048 + kv0 + ks * 32 + g * 8;
        bf16x8 vf = *(const bf16x8*)vr;
        acc_o[0][dt] = mfma16(pf0, vf, acc_o[0][dt]);
        acc_o[1][dt] = mfma16(pf1, vf, acc_o[1][dt]);
      }
    }
  }

  // publish per-wave partial state
  if (l15 == 0) {
#pragma unroll
    for (int h = 0; h < 2; ++h)
#pragma unroll
      for (int r = 0; r < 4; ++r) {
        mL[w][h * 16 + g * 4 + r] = m_run[h][r];
        lL[w][h * 16 + g * 4 + r] = l_run[h][r];
      }
  }
#pragma unroll
  for (int h = 0; h < 2; ++h)
#pragma unroll
    for (int dt = 0; dt < 4; ++dt)
#pragma unroll
      for (int r = 0; r < 4; ++r)
        accL[w][h * 16 + g * 4 + r][dt * 16 + l15] = acc_o[h][dt][r];
  __syncthreads();

  // merge 8 partials: thread -> (row = tid>>4, 4 d's = (tid&15)*4)
  int row = tid >> 4, c0 = (tid & 15) * 4;
  float M = -1e30f;
#pragma unroll
  for (int w2 = 0; w2 < NW; ++w2) M = fmaxf(M, mL[w2][row]);
  float L = 0.f;
  f32x4 o = {0.f, 0.f, 0.f, 0.f};
#pragma unroll
  for (int w2 = 0; w2 < NW; ++w2) {
    float sc = exp2f((mL[w2][row] - M) * L2E);
    L += lL[w2][row] * sc;
    f32x4 a = *(const f32x4*)&accL[w2][row][c0];
    o[0] += sc * a[0]; o[1] += sc * a[1]; o[2] += sc * a[2]; o[3] += sc * a[3];
  }
  float inv = 1.0f / L;
  float4 o4 = {o[0] * inv, o[1] * inv, o[2] * inv, o[3] * inv};
  *(float4*)&Out[(size_t)(b * 2048 + q0 + row) * 64 + c0] = o4;
}

extern "C" void kernel_launch(void* const* d_in, const int* in_sizes, int n_in,
                              void* d_out, int out_size, void* d_ws, size_t ws_size,
                              hipStream_t stream) {
  const float* Xk = (const float*)d_in[0];
  const float* Xv = (const float*)d_in[1];
  const float* Xq = (const float*)d_in[2];
  const float* Wq = (const float*)d_in[3];
  const float* Wk = (const float*)d_in[4];
  const float* Wv = (const float*)d_in[5];
  float* Out = (float*)d_out;

  bf16_t* ws = (bf16_t*)d_ws;
  bf16_t* Qb = ws;                 // [8192][64]   bf16, pre-scaled by 0.125
  bf16_t* Kb = ws + 524288;        // [8192][64]   bf16
  bf16_t* Vt = ws + 1048576;       // [4][64][2048] bf16 (V transposed)
  bf16_t* Wt = ws + 1572864;       // [3][64][1024] bf16 (weights transposed)

  wt_kernel<<<dim3(768), dim3(256), 0, stream>>>(Wq, Wk, Wv, Wt);
  proj_kernel<<<dim3(256), dim3(384), 0, stream>>>(Xq, Xk, Xv, Wt, Qb, Kb, Vt);
  attn_kernel<<<dim3(64, 4), dim3(512), 0, stream>>>(Qb, Kb, Vt, Out);
}